// Round 3
// baseline (549.528 us; speedup 1.0000x reference)
//
#include <hip/hip_runtime.h>
#include <cfloat>

#define NUM_EMB 50
#define EMB_DIM 192
#define ESTRIDE 196  // padded LDS stride (keeps rows 16B-aligned: 196*4 = 49*16)

// ((r0+r1)+(r2+r3))+((r4+r5)+(r6+r7)) — numpy's 8-accumulator combine tree
__device__ __forceinline__ float np_tree8(const float r[8]) {
#pragma clang fp contract(off)
    return ((r[0] + r[1]) + (r[2] + r[3])) + ((r[4] + r[5]) + (r[6] + r[7]));
}

// Bit-exact replica of np.sum(v*v) over 192 contiguous floats:
// pairwise halves of 96, each = 8 stride-8 accumulators + combine tree;
// products rounded separately (contract off).
__device__ float np_sumsq_192(const float* __restrict__ p) {
#pragma clang fp contract(off)
    float tot[2];
#pragma unroll
    for (int h = 0; h < 2; ++h) {
        float r[8];
#pragma unroll
        for (int l = 0; l < 8; ++l) r[l] = 0.f;
        const float* q = p + h * 96;
        for (int t = 0; t < 12; ++t)
#pragma unroll
            for (int l = 0; l < 8; ++l) {
                float v = q[t * 8 + l];
                float pr = v * v;
                r[l] = r[l] + pr;
            }
        tot[h] = np_tree8(r);
    }
    return tot[0] + tot[1];
}

// One thread per row, x row FORCED resident in registers, k-loop outer.
//
// R1/R2 post-mortem: the compiler rematerializes x loads inside the k-loop
// (legal: x is const __restrict__), re-streaming 25 x 201MB through L2 ->
// L2-bandwidth bound ~187us (R1), worse with halved occupancy (R2, 289us).
// Fix: after loading xr[48], an empty `asm volatile("" : "+v"(..))` on every
// component marks the values as potentially modified -> any later use MUST
// read the register; reloading from global is no longer sound. k-loop kept
// ROLLED (#pragma unroll 1) so the e-operand pressure stays ~24 regs and the
// 192 pinned x regs + accs fit the 256-VGPR budget of launch_bounds(256,2).
__global__ __launch_bounds__(256, 2) void vq_fused(
    const float* __restrict__ x, const float* __restrict__ ew,
    float* __restrict__ out_q, float* __restrict__ out_idx,
    float* __restrict__ out_loss, int N)
{
    __shared__ __align__(16) float sE[NUM_EMB * ESTRIDE];  // for sB + output write
    __shared__ float sB[NUM_EMB];

    for (int i = threadIdx.x; i < NUM_EMB * EMB_DIM; i += blockDim.x) {
        int k = i / EMB_DIM, j = i - k * EMB_DIM;
        sE[k * ESTRIDE + j] = ew[i];
    }
    __syncthreads();
    if (threadIdx.x < NUM_EMB)
        sB[threadIdx.x] = np_sumsq_192(&sE[threadIdx.x * ESTRIDE]);  // row contiguous
    __syncthreads();

    const int row = blockIdx.x * blockDim.x + threadIdx.x;  // grid = N/256 exact
    const float4* xg = (const float4*)(x + (size_t)row * EMB_DIM);

    // ---- load full x row into registers (the ONLY x read), then PIN ----
    float4 xr[48];
#pragma unroll
    for (int q = 0; q < 48; ++q) xr[q] = xg[q];
#pragma unroll
    for (int q = 0; q < 48; ++q)
        asm volatile("" : "+v"(xr[q].x), "+v"(xr[q].y), "+v"(xr[q].z), "+v"(xr[q].w));

    // ---- a = np.sum(x*x) with exact numpy pairwise structure ----
    float a;
    {
#pragma clang fp contract(off)
        float tot[2];
#pragma unroll
        for (int h = 0; h < 2; ++h) {
            float r[8];
#pragma unroll
            for (int l = 0; l < 8; ++l) r[l] = 0.f;
#pragma unroll
            for (int t = 0; t < 12; ++t) {
                // elements h*96 + t*8 + [0..7] = two consecutive float4
                const float4 va = xr[h * 24 + t * 2];
                const float4 vb = xr[h * 24 + t * 2 + 1];
                float p0 = va.x * va.x; r[0] = r[0] + p0;
                float p1 = va.y * va.y; r[1] = r[1] + p1;
                float p2 = va.z * va.z; r[2] = r[2] + p2;
                float p3 = va.w * va.w; r[3] = r[3] + p3;
                float p4 = vb.x * vb.x; r[4] = r[4] + p4;
                float p5 = vb.y * vb.y; r[5] = r[5] + p5;
                float p6 = vb.z * vb.z; r[6] = r[6] + p6;
                float p7 = vb.w * vb.w; r[7] = r[7] + p7;
            }
            tot[h] = np_tree8(r);
        }
        a = tot[0] + tot[1];
    }

    // ---- k-loop outer: 2 interleaved sequential-FMA dot chains per iter ----
    // Chain order per k is ascending j (numpy/BLAS sgemm order) — bit-exact.
    // 2 chains x 4-cyc dep latency = 1 FMA issue per 2 cyc = full wave64 issue
    // rate: one wave saturates its SIMD; 2 waves/SIMD cover e-load bubbles.
    float best = FLT_MAX; int bidx = 0;
#pragma unroll 1
    for (int kp = 0; kp < NUM_EMB / 2; ++kp) {
        const float* e0 = ew + (size_t)(2 * kp) * EMB_DIM;
        const float* e1 = e0 + EMB_DIM;
        float a0 = 0.f, a1 = 0.f;
#pragma unroll
        for (int q = 0; q < 48; ++q) {
            const float4 ea = *(const float4*)&e0[q * 4];  // wave-uniform
            const float4 eb = *(const float4*)&e1[q * 4];  // wave-uniform
            const float4 xv = xr[q];
            a0 = __builtin_fmaf(xv.x, ea.x, a0);
            a0 = __builtin_fmaf(xv.y, ea.y, a0);
            a0 = __builtin_fmaf(xv.z, ea.z, a0);
            a0 = __builtin_fmaf(xv.w, ea.w, a0);
            a1 = __builtin_fmaf(xv.x, eb.x, a1);
            a1 = __builtin_fmaf(xv.y, eb.y, a1);
            a1 = __builtin_fmaf(xv.z, eb.z, a1);
            a1 = __builtin_fmaf(xv.w, eb.w, a1);
        }
        {
#pragma clang fp contract(off)
            const float sb0 = sB[2 * kp], sb1 = sB[2 * kp + 1];
            float t0 = a + sb0;       // fl(a + b_k)
            float u0 = 2.0f * a0;     // exact x2
            float d0 = t0 - u0;       // fl(t1 - u)
            if (d0 < best) { best = d0; bidx = 2 * kp; }      // strict <
            float t1 = a + sb1;
            float u1 = 2.0f * a1;
            float d1 = t1 - u1;
            if (d1 < best) { best = d1; bidx = 2 * kp + 1; }  // strict <
        }
    }
    out_idx[row] = (float)bidx;

    // ---- loss: per-wave shuffle reduce + one atomic ----
    float contrib = best;
#pragma unroll
    for (int off = 1; off < 64; off <<= 1) contrib += __shfl_xor(contrib, off);
    if ((threadIdx.x & 63) == 0) atomicAdd(out_loss, contrib);

    // ---- fused coalesced quantized-row write (octet pattern) ----
    {
        const int lane = threadIdx.x & 63;
        const int c = lane & 7;
        const int rr = lane >> 3;
        const int waveRow0 = row & ~63;  // first row owned by this wave
#pragma unroll
        for (int g = 0; g < 8; ++g) {
            const int kk = __shfl(bidx, g * 8 + rr);
            const int wrow = waveRow0 + g * 8 + rr;
            float4* qrow = (float4*)(out_q + (size_t)wrow * EMB_DIM);
            const float* erow = &sE[kk * ESTRIDE];
#pragma unroll
            for (int t = 0; t < 6; ++t)
                qrow[c + 8 * t] = *(const float4*)&erow[(c + 8 * t) * 4];
        }
    }
}

__global__ void vq_init(float* out_loss) { out_loss[0] = 0.f; out_loss[1] = 0.f; }

__global__ void vq_finalize(float* __restrict__ out_loss, int N)
{
    double mean = (double)out_loss[0] / ((double)N * (double)EMB_DIM);
    out_loss[0] = (float)(1.25 * mean);  // (1 + BETA) * mean min-dist / elems
    out_loss[1] = 0.f;                   // contrastloss
}

extern "C" void kernel_launch(void* const* d_in, const int* in_sizes, int n_in,
                              void* d_out, int out_size, void* d_ws, size_t ws_size,
                              hipStream_t stream)
{
    const float* x  = (const float*)d_in[0];
    const float* ew = (const float*)d_in[1];
    const int N = in_sizes[0] / EMB_DIM;  // 262144 (divisible by 256)

    float* out_q    = (float*)d_out;
    float* out_idx  = out_q + (size_t)N * EMB_DIM;
    float* out_loss = out_idx + N;

    vq_init<<<1, 1, 0, stream>>>(out_loss);
    vq_fused<<<N / 256, 256, 0, stream>>>(x, ew, out_q, out_idx, out_loss, N);
    vq_finalize<<<1, 1, 0, stream>>>(out_loss, N);
}

// Round 4
// 442.930 us; speedup vs baseline: 1.2407x; 1.2407x over previous
//
#include <hip/hip_runtime.h>
#include <cfloat>

#define NUM_EMB 50
#define EMB_DIM 192
#define ESTRIDE 196  // padded LDS stride (keeps rows 16B-aligned: 196*4 = 49*16)

typedef __attribute__((ext_vector_type(8))) float sf8;  // 8 floats in SGPRs

// ((r0+r1)+(r2+r3))+((r4+r5)+(r6+r7)) — numpy's 8-accumulator combine tree
__device__ __forceinline__ float np_tree8(const float r[8]) {
#pragma clang fp contract(off)
    return ((r[0] + r[1]) + (r[2] + r[3])) + ((r[4] + r[5]) + (r[6] + r[7]));
}

// Bit-exact replica of np.sum(v*v) over 192 contiguous floats:
// pairwise halves of 96, each = 8 stride-8 accumulators + combine tree;
// products rounded separately (contract off).
__device__ float np_sumsq_192(const float* __restrict__ p) {
#pragma clang fp contract(off)
    float tot[2];
#pragma unroll
    for (int h = 0; h < 2; ++h) {
        float r[8];
#pragma unroll
        for (int l = 0; l < 8; ++l) r[l] = 0.f;
        const float* q = p + h * 96;
        for (int t = 0; t < 12; ++t)
#pragma unroll
            for (int l = 0; l < 8; ++l) {
                float v = q[t * 8 + l];
                float pr = v * v;
                r[l] = r[l] + pr;
            }
        tot[h] = np_tree8(r);
    }
    return tot[0] + tot[1];
}

// R0 structure (acc[50] resident, m-chunked x) with BOTH pressure drivers fixed:
//  - e operand delivered via s_load_dwordx8 into SGPRs (scalar pipe, wave-
//    uniform addresses). No VGPR e-loads -> no hoisting-driven spills, and the
//    VMEM/L1 pipe is freed entirely for x.
//  - x chunk (32 floats) pinned with empty asm per m-iteration -> remat of
//    per-lane x loads inside the k-body (R0/R1's 190us L1 wall) is impossible.
// SMEM completes OUT OF ORDER -> only lgkmcnt(0) is a safe wait; we amortize
// it over 2 embeddings (8 loads -> 1 wait -> 64 FMAs). The wait asm holds the
// e-vectors as "+s" so FMAs are dataflow-ordered after the wait (rule #18).
// True VGPR pressure ~110 (50 acc + 32 x + temps) << 256 budget of (256,2).
__global__ __launch_bounds__(256, 2) void vq_fused(
    const float* __restrict__ x, const float* __restrict__ ew,
    float* __restrict__ out_q, float* __restrict__ out_idx,
    float* __restrict__ out_loss, int N)
{
    __shared__ __align__(16) float sE[NUM_EMB * ESTRIDE];  // for sB + output write
    __shared__ float sB[NUM_EMB];

    for (int i = threadIdx.x; i < NUM_EMB * EMB_DIM; i += blockDim.x) {
        int k = i / EMB_DIM, j = i - k * EMB_DIM;
        sE[k * ESTRIDE + j] = ew[i];
    }
    __syncthreads();
    if (threadIdx.x < NUM_EMB)
        sB[threadIdx.x] = np_sumsq_192(&sE[threadIdx.x * ESTRIDE]);  // row contiguous
    __syncthreads();

    const int row = blockIdx.x * blockDim.x + threadIdx.x;  // grid = N/256 exact
    const float4* xr = (const float4*)(x + (size_t)row * EMB_DIM);

    float acc[NUM_EMB];
#pragma unroll
    for (int k = 0; k < NUM_EMB; ++k) acc[k] = 0.f;

    float rA[8];
    float aHalf[2];

    const float* ebase = ew;  // advances by 32 floats per m (SGPR pair)

#pragma unroll 1
    for (int m = 0; m < 6; ++m) {  // 6 chunks of 32 floats (one 128B line each)
        float4 f4[8];
#pragma unroll
        for (int q = 0; q < 8; ++q) f4[q] = xr[m * 8 + q];
        // Pin the chunk: remat of these loads inside the k-body is now illegal.
#pragma unroll
        for (int q = 0; q < 8; ++q)
            asm volatile("" : "+v"(f4[q].x), "+v"(f4[q].y), "+v"(f4[q].z), "+v"(f4[q].w));

        // ||x||^2 partials, numpy pairwise structure (halves at m=0..2, 3..5)
        if ((m % 3) == 0) {
#pragma unroll
            for (int l = 0; l < 8; ++l) rA[l] = 0.f;
        }
        {
#pragma clang fp contract(off)
#pragma unroll
            for (int q = 0; q < 8; ++q) {
                float p0 = f4[q].x * f4[q].x; rA[(q * 4 + 0) & 7] = rA[(q * 4 + 0) & 7] + p0;
                float p1 = f4[q].y * f4[q].y; rA[(q * 4 + 1) & 7] = rA[(q * 4 + 1) & 7] + p1;
                float p2 = f4[q].z * f4[q].z; rA[(q * 4 + 2) & 7] = rA[(q * 4 + 2) & 7] + p2;
                float p3 = f4[q].w * f4[q].w; rA[(q * 4 + 3) & 7] = rA[(q * 4 + 3) & 7] + p3;
            }
        }
        if ((m % 3) == 2) aHalf[m / 3] = np_tree8(rA);

        // Two embeddings per wait: 8 s_load_dwordx8 -> lgkmcnt(0) -> 64 FMAs.
        // Byte offsets from ebase: k*768 + h*32 (<=38K, fits 20-bit imm).
        // FMA chain order per k: j ascending (numpy/BLAS order) — bit-exact.
#pragma unroll
        for (int kk = 0; kk < NUM_EMB; kk += 2) {
            sf8 ea[4], eb[4];
#pragma unroll
            for (int h = 0; h < 4; ++h)
                asm volatile("s_load_dwordx8 %0, %1, %2"
                             : "=s"(ea[h]) : "s"(ebase), "n"(kk * 768 + h * 32));
#pragma unroll
            for (int h = 0; h < 4; ++h)
                asm volatile("s_load_dwordx8 %0, %1, %2"
                             : "=s"(eb[h]) : "s"(ebase), "n"(kk * 768 + 768 + h * 32));
            asm volatile("s_waitcnt lgkmcnt(0)"
                         : "+s"(ea[0]), "+s"(ea[1]), "+s"(ea[2]), "+s"(ea[3]),
                           "+s"(eb[0]), "+s"(eb[1]), "+s"(eb[2]), "+s"(eb[3]));
#pragma unroll
            for (int h = 0; h < 4; ++h) {  // j = h*8 .. h*8+7 for k = kk
                const float4 xa = f4[h * 2], xb = f4[h * 2 + 1];
                acc[kk] = __builtin_fmaf(xa.x, ea[h][0], acc[kk]);
                acc[kk] = __builtin_fmaf(xa.y, ea[h][1], acc[kk]);
                acc[kk] = __builtin_fmaf(xa.z, ea[h][2], acc[kk]);
                acc[kk] = __builtin_fmaf(xa.w, ea[h][3], acc[kk]);
                acc[kk] = __builtin_fmaf(xb.x, ea[h][4], acc[kk]);
                acc[kk] = __builtin_fmaf(xb.y, ea[h][5], acc[kk]);
                acc[kk] = __builtin_fmaf(xb.z, ea[h][6], acc[kk]);
                acc[kk] = __builtin_fmaf(xb.w, ea[h][7], acc[kk]);
            }
#pragma unroll
            for (int h = 0; h < 4; ++h) {  // j = h*8 .. h*8+7 for k = kk+1
                const float4 xa = f4[h * 2], xb = f4[h * 2 + 1];
                acc[kk + 1] = __builtin_fmaf(xa.x, eb[h][0], acc[kk + 1]);
                acc[kk + 1] = __builtin_fmaf(xa.y, eb[h][1], acc[kk + 1]);
                acc[kk + 1] = __builtin_fmaf(xa.z, eb[h][2], acc[kk + 1]);
                acc[kk + 1] = __builtin_fmaf(xa.w, eb[h][3], acc[kk + 1]);
                acc[kk + 1] = __builtin_fmaf(xb.x, eb[h][4], acc[kk + 1]);
                acc[kk + 1] = __builtin_fmaf(xb.y, eb[h][5], acc[kk + 1]);
                acc[kk + 1] = __builtin_fmaf(xb.z, eb[h][6], acc[kk + 1]);
                acc[kk + 1] = __builtin_fmaf(xb.w, eb[h][7], acc[kk + 1]);
            }
        }
        ebase += 32;
    }

    float best; int bidx;
    {
#pragma clang fp contract(off)
        float a = aHalf[0] + aHalf[1];
        best = FLT_MAX; bidx = 0;
#pragma unroll
        for (int k = 0; k < NUM_EMB; ++k) {
            float t1 = a + sB[k];     // fl(a + b_k)
            float u  = 2.0f * acc[k]; // exact x2
            float d  = t1 - u;        // fl(t1 - u)
            if (d < best) { best = d; bidx = k; }  // strict <: first-index ties
        }
    }
    out_idx[row] = (float)bidx;

    // loss: per-wave shuffle reduce + one atomic
    float contrib = best;
#pragma unroll
    for (int off = 1; off < 64; off <<= 1) contrib += __shfl_xor(contrib, off);
    if ((threadIdx.x & 63) == 0) atomicAdd(out_loss, contrib);

    // fused coalesced quantized-row write (octet pattern)
    {
        const int lane = threadIdx.x & 63;
        const int c = lane & 7;
        const int rr = lane >> 3;
        const int waveRow0 = row & ~63;  // first row owned by this wave
#pragma unroll
        for (int g = 0; g < 8; ++g) {
            const int kk = __shfl(bidx, g * 8 + rr);
            const int wrow = waveRow0 + g * 8 + rr;
            float4* qrow = (float4*)(out_q + (size_t)wrow * EMB_DIM);
            const float* erow = &sE[kk * ESTRIDE];
#pragma unroll
            for (int t = 0; t < 6; ++t)
                qrow[c + 8 * t] = *(const float4*)&erow[(c + 8 * t) * 4];
        }
    }
}

__global__ void vq_init(float* out_loss) { out_loss[0] = 0.f; out_loss[1] = 0.f; }

__global__ void vq_finalize(float* __restrict__ out_loss, int N)
{
    double mean = (double)out_loss[0] / ((double)N * (double)EMB_DIM);
    out_loss[0] = (float)(1.25 * mean);  // (1 + BETA) * mean min-dist / elems
    out_loss[1] = 0.f;                   // contrastloss
}

extern "C" void kernel_launch(void* const* d_in, const int* in_sizes, int n_in,
                              void* d_out, int out_size, void* d_ws, size_t ws_size,
                              hipStream_t stream)
{
    const float* x  = (const float*)d_in[0];
    const float* ew = (const float*)d_in[1];
    const int N = in_sizes[0] / EMB_DIM;  // 262144 (divisible by 256)

    float* out_q    = (float*)d_out;
    float* out_idx  = out_q + (size_t)N * EMB_DIM;
    float* out_loss = out_idx + N;

    vq_init<<<1, 1, 0, stream>>>(out_loss);
    vq_fused<<<N / 256, 256, 0, stream>>>(x, ew, out_q, out_idx, out_loss, N);
    vq_finalize<<<1, 1, 0, stream>>>(out_loss, N);
}

// Round 5
// 384.721 us; speedup vs baseline: 1.4284x; 1.1513x over previous
//
#include <hip/hip_runtime.h>
#include <cfloat>

#define NUM_EMB 50
#define EMB_DIM 192
#define ESTRIDE 196  // padded LDS stride (rows stay contiguous; 196*4 = 49*16)

// ((r0+r1)+(r2+r3))+((r4+r5)+(r6+r7)) — numpy's 8-accumulator combine tree
__device__ __forceinline__ float np_tree8(const float r[8]) {
#pragma clang fp contract(off)
    return ((r[0] + r[1]) + (r[2] + r[3])) + ((r[4] + r[5]) + (r[6] + r[7]));
}

// Bit-exact replica of np.sum(v*v) over 192 contiguous floats:
// pairwise halves of 96, each = 8 stride-8 accumulators + combine tree;
// products rounded separately (contract off).
__device__ float np_sumsq_192(const float* __restrict__ p) {
#pragma clang fp contract(off)
    float tot[2];
#pragma unroll
    for (int h = 0; h < 2; ++h) {
        float r[8];
#pragma unroll
        for (int l = 0; l < 8; ++l) r[l] = 0.f;
        const float* q = p + h * 96;
        for (int t = 0; t < 12; ++t)
#pragma unroll
            for (int l = 0; l < 8; ++l) {
                float v = q[t * 8 + l];
                float pr = v * v;
                r[l] = r[l] + pr;
            }
        tot[h] = np_tree8(r);
    }
    return tot[0] + tot[1];
}

// TWO ROWS PER THREAD. R0-R4 post-mortem: every variant (LDS broadcast / VMEM
// uniform / SMEM s_load) is e-operand-DELIVERY bound at ~190-220us, because
// delivery cost is per-wave (each wave re-reads the 38KB table 6x: 2400
// broadcast ds_read_b128 @ ~12cyc = ~29k cyc/wave; x16 waves/CU = 460k cyc
// ~ the whole kernel). FMA floor is only 77k cyc/SIMD. Fix: amortize each
// delivered e over 2 rows -> DS cost per row halves (expected ~96us floor),
// FMA work (2x) hides underneath. VGPR: 100 acc + 64 x + temps ~ 210 < 256
// budget of (256,2); R=3 would not fit. x chunks pinned (R4-proven) so the
// compiler cannot rematerialize per-lane x loads inside the k-body.
__global__ __launch_bounds__(256, 2) void vq_fused(
    const float* __restrict__ x, const float* __restrict__ ew,
    float* __restrict__ out_q, float* __restrict__ out_idx,
    float* __restrict__ out_loss, int N)
{
    __shared__ __align__(16) float sE[NUM_EMB * ESTRIDE];  // broadcast reads + writer
    __shared__ float sB[NUM_EMB];

    for (int i = threadIdx.x; i < NUM_EMB * EMB_DIM; i += blockDim.x) {
        int k = i / EMB_DIM, j = i - k * EMB_DIM;
        sE[k * ESTRIDE + j] = ew[i];
    }
    __syncthreads();
    if (threadIdx.x < NUM_EMB)
        sB[threadIdx.x] = np_sumsq_192(&sE[threadIdx.x * ESTRIDE]);  // row contiguous
    __syncthreads();

    // grid = N/512 blocks; thread owns rows r0 (first half) and r0 + N/2.
    const int r0 = blockIdx.x * blockDim.x + threadIdx.x;
    const int half = N >> 1;
    const float4* xg0 = (const float4*)(x + (size_t)r0 * EMB_DIM);
    const float4* xg1 = (const float4*)(x + (size_t)(r0 + half) * EMB_DIM);

    float acc0[NUM_EMB], acc1[NUM_EMB];
#pragma unroll
    for (int k = 0; k < NUM_EMB; ++k) { acc0[k] = 0.f; acc1[k] = 0.f; }

    float rA0[8], rA1[8];
    float aHalf0[2], aHalf1[2];

#pragma unroll 1
    for (int m = 0; m < 6; ++m) {  // 6 chunks of 32 floats per row
        float4 fa[8], fb[8];
#pragma unroll
        for (int q = 0; q < 8; ++q) fa[q] = xg0[m * 8 + q];
#pragma unroll
        for (int q = 0; q < 8; ++q) fb[q] = xg1[m * 8 + q];
        // Pin both chunks: remat of x loads inside the k-body is illegal.
#pragma unroll
        for (int q = 0; q < 8; ++q)
            asm volatile("" : "+v"(fa[q].x), "+v"(fa[q].y), "+v"(fa[q].z), "+v"(fa[q].w));
#pragma unroll
        for (int q = 0; q < 8; ++q)
            asm volatile("" : "+v"(fb[q].x), "+v"(fb[q].y), "+v"(fb[q].z), "+v"(fb[q].w));

        // ||x||^2 partials, numpy pairwise structure (halves at m=0..2, 3..5)
        if ((m % 3) == 0) {
#pragma unroll
            for (int l = 0; l < 8; ++l) { rA0[l] = 0.f; rA1[l] = 0.f; }
        }
        {
#pragma clang fp contract(off)
#pragma unroll
            for (int q = 0; q < 8; ++q) {
                float p0 = fa[q].x * fa[q].x; rA0[(q * 4 + 0) & 7] = rA0[(q * 4 + 0) & 7] + p0;
                float p1 = fa[q].y * fa[q].y; rA0[(q * 4 + 1) & 7] = rA0[(q * 4 + 1) & 7] + p1;
                float p2 = fa[q].z * fa[q].z; rA0[(q * 4 + 2) & 7] = rA0[(q * 4 + 2) & 7] + p2;
                float p3 = fa[q].w * fa[q].w; rA0[(q * 4 + 3) & 7] = rA0[(q * 4 + 3) & 7] + p3;
            }
#pragma unroll
            for (int q = 0; q < 8; ++q) {
                float p0 = fb[q].x * fb[q].x; rA1[(q * 4 + 0) & 7] = rA1[(q * 4 + 0) & 7] + p0;
                float p1 = fb[q].y * fb[q].y; rA1[(q * 4 + 1) & 7] = rA1[(q * 4 + 1) & 7] + p1;
                float p2 = fb[q].z * fb[q].z; rA1[(q * 4 + 2) & 7] = rA1[(q * 4 + 2) & 7] + p2;
                float p3 = fb[q].w * fb[q].w; rA1[(q * 4 + 3) & 7] = rA1[(q * 4 + 3) & 7] + p3;
            }
        }
        if ((m % 3) == 2) { aHalf0[m / 3] = np_tree8(rA0); aHalf1[m / 3] = np_tree8(rA1); }

        // Per (m,k): 8 broadcast ds_read_b128, each reused for BOTH rows'
        // sequential-FMA chains (j ascending per k — bit-exact numpy order).
#pragma unroll
        for (int k = 0; k < NUM_EMB; ++k) {
            const float* ek = &sE[k * ESTRIDE + m * 32];
            float4 e4[8];
#pragma unroll
            for (int h = 0; h < 8; ++h) e4[h] = *(const float4*)&ek[h * 4];
#pragma unroll
            for (int h = 0; h < 8; ++h) {
                acc0[k] = __builtin_fmaf(fa[h].x, e4[h].x, acc0[k]);
                acc0[k] = __builtin_fmaf(fa[h].y, e4[h].y, acc0[k]);
                acc0[k] = __builtin_fmaf(fa[h].z, e4[h].z, acc0[k]);
                acc0[k] = __builtin_fmaf(fa[h].w, e4[h].w, acc0[k]);
            }
#pragma unroll
            for (int h = 0; h < 8; ++h) {
                acc1[k] = __builtin_fmaf(fb[h].x, e4[h].x, acc1[k]);
                acc1[k] = __builtin_fmaf(fb[h].y, e4[h].y, acc1[k]);
                acc1[k] = __builtin_fmaf(fb[h].z, e4[h].z, acc1[k]);
                acc1[k] = __builtin_fmaf(fb[h].w, e4[h].w, acc1[k]);
            }
        }
    }

    float best0, best1; int bidx0, bidx1;
    {
#pragma clang fp contract(off)
        float a0 = aHalf0[0] + aHalf0[1];
        float a1 = aHalf1[0] + aHalf1[1];
        best0 = FLT_MAX; bidx0 = 0;
        best1 = FLT_MAX; bidx1 = 0;
#pragma unroll
        for (int k = 0; k < NUM_EMB; ++k) {
            float sb = sB[k];
            float t0 = a0 + sb;        // fl(a + b_k)
            float u0 = 2.0f * acc0[k]; // exact x2
            float d0 = t0 - u0;        // fl(t1 - u)
            if (d0 < best0) { best0 = d0; bidx0 = k; }  // strict <: first-index ties
            float t1 = a1 + sb;
            float u1 = 2.0f * acc1[k];
            float d1 = t1 - u1;
            if (d1 < best1) { best1 = d1; bidx1 = k; }
        }
    }
    out_idx[r0] = (float)bidx0;
    out_idx[r0 + half] = (float)bidx1;

    // loss: per-wave shuffle reduce + one atomic (pre-add both rows)
    float contrib = best0 + best1;
#pragma unroll
    for (int off = 1; off < 64; off <<= 1) contrib += __shfl_xor(contrib, off);
    if ((threadIdx.x & 63) == 0) atomicAdd(out_loss, contrib);

    // fused coalesced quantized-row write (octet pattern), both halves
    {
        const int lane = threadIdx.x & 63;
        const int c = lane & 7;
        const int rr = lane >> 3;
        const int waveRow0 = r0 & ~63;  // first row owned by this wave (half 0)
#pragma unroll
        for (int g = 0; g < 8; ++g) {
            const int kk = __shfl(bidx0, g * 8 + rr);
            const int wrow = waveRow0 + g * 8 + rr;
            float4* qrow = (float4*)(out_q + (size_t)wrow * EMB_DIM);
            const float* erow = &sE[kk * ESTRIDE];
#pragma unroll
            for (int t = 0; t < 6; ++t)
                qrow[c + 8 * t] = *(const float4*)&erow[(c + 8 * t) * 4];
        }
#pragma unroll
        for (int g = 0; g < 8; ++g) {
            const int kk = __shfl(bidx1, g * 8 + rr);
            const int wrow = waveRow0 + half + g * 8 + rr;
            float4* qrow = (float4*)(out_q + (size_t)wrow * EMB_DIM);
            const float* erow = &sE[kk * ESTRIDE];
#pragma unroll
            for (int t = 0; t < 6; ++t)
                qrow[c + 8 * t] = *(const float4*)&erow[(c + 8 * t) * 4];
        }
    }
}

__global__ void vq_init(float* out_loss) { out_loss[0] = 0.f; out_loss[1] = 0.f; }

__global__ void vq_finalize(float* __restrict__ out_loss, int N)
{
    double mean = (double)out_loss[0] / ((double)N * (double)EMB_DIM);
    out_loss[0] = (float)(1.25 * mean);  // (1 + BETA) * mean min-dist / elems
    out_loss[1] = 0.f;                   // contrastloss
}

extern "C" void kernel_launch(void* const* d_in, const int* in_sizes, int n_in,
                              void* d_out, int out_size, void* d_ws, size_t ws_size,
                              hipStream_t stream)
{
    const float* x  = (const float*)d_in[0];
    const float* ew = (const float*)d_in[1];
    const int N = in_sizes[0] / EMB_DIM;  // 262144 (divisible by 512)

    float* out_q    = (float*)d_out;
    float* out_idx  = out_q + (size_t)N * EMB_DIM;
    float* out_loss = out_idx + N;

    vq_init<<<1, 1, 0, stream>>>(out_loss);
    vq_fused<<<N / 512, 256, 0, stream>>>(x, ew, out_q, out_idx, out_loss, N);
    vq_finalize<<<1, 1, 0, stream>>>(out_loss, N);
}